// Round 9
// baseline (128.372 us; speedup 1.0000x reference)
//
#include <hip/hip_runtime.h>
#include <hip/hip_bf16.h>
#include <stdint.h>

// Problem constants
#define LL   4096
#define CCH  64
#define DOUT 512
#define MM   8192            // B*NP patch-rows
#define TT   0.001f          // 1/FS

using bf16 = __hip_bfloat16;
typedef __attribute__((ext_vector_type(8))) short bf16x8;
typedef __attribute__((ext_vector_type(4))) float f32x4;
typedef __attribute__((ext_vector_type(4))) float fvec4;   // native vec for nt builtins

#define MFMA(a, b, c) __builtin_amdgcn_mfma_f32_16x16x32_bf16((a), (b), (c), 0, 0, 0)

__device__ __forceinline__ uint2 pack4_bf16(float a, float b, float c, float d) {
    union { bf16 h[4]; uint2 u; } p;
    p.h[0] = __float2bfloat16(a);
    p.h[1] = __float2bfloat16(b);
    p.h[2] = __float2bfloat16(c);
    p.h[3] = __float2bfloat16(d);
    return p.u;
}

// ---------------------------------------------------------------------------
// prep: repack weights into k-chunked layout (chunk = 32 k's, contiguous per
// col) so a wave's B-fragment global load is one contiguous 1 KB block:
//   w1g[ic][col][kk]  (ic=0..31): = w1[col][l*32+j], k=ic*32+kk, l=k>>4,j=k&15
//   w2g[ic2][col][kk] (ic2=0..15): = w2[col][ic2*32+kk]
//   blocks [768,896): A1[o] = T*sum_l Wt[o][l]; C1[o] = b1[o]+T*sum_l l*Wt
// ---------------------------------------------------------------------------
__global__ __launch_bounds__(256) void prep(
    const float* __restrict__ w1, const float* __restrict__ b1,
    const float* __restrict__ w2,
    bf16* __restrict__ w1g, bf16* __restrict__ w2g,
    float* __restrict__ A1, float* __restrict__ C1)
{
    const int blk = blockIdx.x;
    if (blk < 512) {
        int g   = blk * 256 + threadIdx.x;          // 0..131071, 4 elems each
        int kk0 = (g & 7) * 4;                      // 0,4,..,28
        int col = (g >> 3) & 511;
        int ic  = g >> 12;                          // 0..31
        int l   = ic * 2 + (kk0 >> 4);
        int j0  = kk0 & 15;
        float4 v = *(const float4*)(w1 + (size_t)col * 2048 + l * 32 + j0);
        *(uint2*)(w1g + ((size_t)(ic * 512 + col) * 32 + kk0)) =
            pack4_bf16(v.x, v.y, v.z, v.w);
    } else if (blk < 768) {
        int g   = (blk - 512) * 256 + threadIdx.x;  // 0..65535
        int kk0 = (g & 7) * 4;
        int col = (g >> 3) & 511;
        int ic2 = g >> 12;                          // 0..15
        float4 v = *(const float4*)(w2 + (size_t)col * 512 + ic2 * 32 + kk0);
        *(uint2*)(w2g + ((size_t)(ic2 * 512 + col) * 32 + kk0)) =
            pack4_bf16(v.x, v.y, v.z, v.w);
    } else {
        const int o = (blk - 768) * 4 + (threadIdx.x >> 6);
        const int l = threadIdx.x & 63;
        const float* wr = w1 + (size_t)o * 2048 + l * 32 + 16;
        float s0 = 0.f;
#pragma unroll
        for (int j = 0; j < 16; ++j) s0 += wr[j];
        float s1 = (float)l * s0;
#pragma unroll
        for (int off = 32; off > 0; off >>= 1) {
            s0 += __shfl_down(s0, off);
            s1 += __shfl_down(s1, off);
        }
        if (l == 0) {
            A1[o] = TT * s0;
            C1[o] = b1[o] + TT * s1;
        }
    }
}

// ---------------------------------------------------------------------------
// Megakernel v4: block = 32 patches x 512 outputs, both layers fused.
// - Prologue: gather x (NON-TEMPORAL loads, keeps weights L2-hot) ->
//   bf16 A-tile (32x1024, XOR-8 swizzled) in LDS, once.
// - Phase A (32 k32-chunks): B-frags global->VGPR, two-buffer parity
//   pipeline with NO register copies (consume bufP -> MFMAs -> reload bufP
//   for chunk+2), A-frags from LDS. No barriers inside the loop.
// - Hs (32x512) overlays A; Phase B (16 chunks) identical structure vs w2g.
// 3 __syncthreads total. LDS = 64 KB.
// ---------------------------------------------------------------------------
__global__ __launch_bounds__(512, 2) void mega(
    const float* __restrict__ x, const int* __restrict__ sLg,
    const int* __restrict__ sCg, const bf16* __restrict__ w1g,
    const bf16* __restrict__ w2g, const float* __restrict__ A1,
    const float* __restrict__ C1, const float* __restrict__ b2,
    float* __restrict__ out)
{
    __shared__ __align__(16) bf16 Asm[32 * 1024];   // 64 KB; Hs overlays later
    bf16* const Hs = Asm;                           // 32 x 512 after phase A

    const int t    = threadIdx.x;
    const int lane = t & 63;
    const int wave = t >> 6;            // 0..7, owns cols [wave*64, wave*64+64)
    const int fr   = lane & 15;
    const int fq   = lane >> 4;
    const int m0   = blockIdx.x * 32;
    const int b    = m0 >> 8;           // 32 rows lie within one batch

    // ---- Prologue: gather x into swizzled A-tile (one shot, nt loads)
    {
        const int gr  = t >> 4;         // patch row 0..31
        const int gs  = t & 15;
        const int gsl = sLg[m0 + gr];
        const int gsc = sCg[m0 + gr];
        const float* gx = x + ((size_t)b * LL + gsl + (gs >> 2)) * CCH
                            + gsc + (gs & 3) * 4;
        fvec4 xv[16];
#pragma unroll
        for (int p = 0; p < 16; ++p)
            xv[p] = __builtin_nontemporal_load((const fvec4*)(gx + (size_t)p * 4 * CCH));
#pragma unroll
        for (int p = 0; p < 16; ++p) {
            const int l = 4 * p + (gs >> 2);
            const int u = l * 2 + ((gs & 3) >> 1);          // k-unit = (l*16+j)>>3
            const int idx = gr * 1024 + ((u ^ (gr & 7)) * 8) + (gs & 1) * 4;
            *(uint2*)(Asm + idx) = pack4_bf16(xv[p].x, xv[p].y, xv[p].z, xv[p].w);
        }
    }
    __syncthreads();                    // A-tile ready

    // ---- Phase A: 32 chunks of k=32; two-buffer parity pipeline
    const bf16* const w1b = w1g + (size_t)(wave * 64 + fr) * 32 + fq * 8;
    const int x7 = fr & 7;              // xor key: (row&7) == (fr&7) for i=0,1
    f32x4 acc[2][4] = {};
    {
        bf16x8 bA[4], bB[4];
#pragma unroll
        for (int j = 0; j < 4; ++j)
            bA[j] = *(const bf16x8*)(w1b + j * 512);
#pragma unroll
        for (int j = 0; j < 4; ++j)
            bB[j] = *(const bf16x8*)(w1b + 16384 + j * 512);

#pragma unroll
        for (int it = 0; it < 16; ++it) {
            // sub0: chunk 2it (bA), then reload bA <- chunk 2it+2
            {
                const int u = (2 * it) * 4 + fq;
                bf16x8 af0 = *(const bf16x8*)&Asm[(fr)      * 1024 + ((u ^ x7) * 8)];
                bf16x8 af1 = *(const bf16x8*)&Asm[(16 + fr) * 1024 + ((u ^ x7) * 8)];
#pragma unroll
                for (int j = 0; j < 4; ++j) {
                    acc[0][j] = MFMA(af0, bA[j], acc[0][j]);
                    acc[1][j] = MFMA(af1, bA[j], acc[1][j]);
                }
                if (it < 15) {
                    const bf16* p = w1b + (size_t)(2 * it + 2) * 16384;
#pragma unroll
                    for (int j = 0; j < 4; ++j)
                        bA[j] = *(const bf16x8*)(p + j * 512);
                }
            }
            // sub1: chunk 2it+1 (bB), then reload bB <- chunk 2it+3
            {
                const int u = (2 * it + 1) * 4 + fq;
                bf16x8 af0 = *(const bf16x8*)&Asm[(fr)      * 1024 + ((u ^ x7) * 8)];
                bf16x8 af1 = *(const bf16x8*)&Asm[(16 + fr) * 1024 + ((u ^ x7) * 8)];
#pragma unroll
                for (int j = 0; j < 4; ++j) {
                    acc[0][j] = MFMA(af0, bB[j], acc[0][j]);
                    acc[1][j] = MFMA(af1, bB[j], acc[1][j]);
                }
                if (it < 15) {
                    const bf16* p = w1b + (size_t)(2 * it + 3) * 16384;
#pragma unroll
                    for (int j = 0; j < 4; ++j)
                        bB[j] = *(const bf16x8*)(p + j * 512);
                }
            }
        }
    }
    __syncthreads();                    // all A-frag reads done (Asm -> Hs)

    // ---- Phase A epilogue: silu(acc + sL*A1 + C1) -> Hs (swizzled)
    {
        float slr[2][4];
#pragma unroll
        for (int i = 0; i < 2; ++i)
#pragma unroll
            for (int rr = 0; rr < 4; ++rr)
                slr[i][rr] = (float)sLg[m0 + i * 16 + fq * 4 + rr];
#pragma unroll
        for (int j = 0; j < 4; ++j) {
            const int col = wave * 64 + j * 16 + fr;
            const float av = A1[col];
            const float cv = C1[col];
            const int c8 = col >> 3, c7 = col & 7;
#pragma unroll
            for (int i = 0; i < 2; ++i)
#pragma unroll
                for (int rr = 0; rr < 4; ++rr) {
                    const int row = i * 16 + fq * 4 + rr;
                    float v = acc[i][j][rr] + slr[i][rr] * av + cv;
                    v = v / (1.0f + __expf(-v));
                    Hs[row * 512 + ((c8 ^ (row & 7)) * 8) + c7] = __float2bfloat16(v);
                }
        }
    }
    __syncthreads();                    // Hs ready

    // ---- Phase B: 16 chunks of k=32 vs w2g; same parity pipeline
    const bf16* const w2b = w2g + (size_t)(wave * 64 + fr) * 32 + fq * 8;
    f32x4 acc2[2][4] = {};
    {
        bf16x8 bA[4], bB[4];
#pragma unroll
        for (int j = 0; j < 4; ++j)
            bA[j] = *(const bf16x8*)(w2b + j * 512);
#pragma unroll
        for (int j = 0; j < 4; ++j)
            bB[j] = *(const bf16x8*)(w2b + 16384 + j * 512);

#pragma unroll
        for (int it = 0; it < 8; ++it) {
            {
                const int u = (2 * it) * 4 + fq;
                bf16x8 af0 = *(const bf16x8*)&Hs[(fr)      * 512 + ((u ^ x7) * 8)];
                bf16x8 af1 = *(const bf16x8*)&Hs[(16 + fr) * 512 + ((u ^ x7) * 8)];
#pragma unroll
                for (int j = 0; j < 4; ++j) {
                    acc2[0][j] = MFMA(af0, bA[j], acc2[0][j]);
                    acc2[1][j] = MFMA(af1, bA[j], acc2[1][j]);
                }
                if (it < 7) {
                    const bf16* p = w2b + (size_t)(2 * it + 2) * 16384;
#pragma unroll
                    for (int j = 0; j < 4; ++j)
                        bA[j] = *(const bf16x8*)(p + j * 512);
                }
            }
            {
                const int u = (2 * it + 1) * 4 + fq;
                bf16x8 af0 = *(const bf16x8*)&Hs[(fr)      * 512 + ((u ^ x7) * 8)];
                bf16x8 af1 = *(const bf16x8*)&Hs[(16 + fr) * 512 + ((u ^ x7) * 8)];
#pragma unroll
                for (int j = 0; j < 4; ++j) {
                    acc2[0][j] = MFMA(af0, bB[j], acc2[0][j]);
                    acc2[1][j] = MFMA(af1, bB[j], acc2[1][j]);
                }
                if (it < 7) {
                    const bf16* p = w2b + (size_t)(2 * it + 3) * 16384;
#pragma unroll
                    for (int j = 0; j < 4; ++j)
                        bB[j] = *(const bf16x8*)(p + j * 512);
                }
            }
        }
    }

    // ---- Phase B epilogue: + b2, fp32 out, coalesced nt stores
#pragma unroll
    for (int j = 0; j < 4; ++j) {
        const int col = wave * 64 + j * 16 + fr;
        const float bv = b2[col];
#pragma unroll
        for (int i = 0; i < 2; ++i)
#pragma unroll
            for (int rr = 0; rr < 4; ++rr) {
                const int row = m0 + i * 16 + fq * 4 + rr;
                __builtin_nontemporal_store(acc2[i][j][rr] + bv,
                                            out + (size_t)row * 512 + col);
            }
    }
}

// ---------------------------------------------------------------------------
extern "C" void kernel_launch(void* const* d_in, const int* in_sizes, int n_in,
                              void* d_out, int out_size, void* d_ws, size_t ws_size,
                              hipStream_t stream)
{
    const float* x  = (const float*)d_in[0];
    const int*   sL = (const int*)  d_in[1];
    const int*   sC = (const int*)  d_in[2];
    const float* w1 = (const float*)d_in[3];
    const float* b1 = (const float*)d_in[4];
    const float* w2 = (const float*)d_in[5];
    const float* b2 = (const float*)d_in[6];
    float* out = (float*)d_out;

    char* ws = (char*)d_ws;
    bf16*  w1g = (bf16*)ws;                         // 512*1024*2 = 1 MB
    bf16*  w2g = (bf16*)(ws + (1 << 20));           // 512*512*2  = 0.5 MB
    float* A1  = (float*)(ws + (1 << 20) + (1 << 19));
    float* C1  = A1 + DOUT;

    prep<<<896, 256, 0, stream>>>(w1, b1, w2, w1g, w2g, A1, C1);
    mega<<<MM / 32, 512, 0, stream>>>(x, sL, sC, w1g, w2g, A1, C1, b2, out);
}